// Round 2
// baseline (191.429 us; speedup 1.0000x reference)
//
#include <hip/hip_runtime.h>

// KPConv fused, R12 = R11 architecture (MFMA phase-1 aggregation) with all
// novel instruction semantics removed (R11 failed at 5e28 absmax; the only
// unproven ingredient in the value path was the v_cvt_pk_bf16_f32 inline asm):
//  - agg hi/lo splits via exact TRUNCATION bit math (hi = bits>>16, residual
//    Sterbenz-exact, lo = trunc(residual)) -> rel err ~2^-16, no asm.
//  - dump conversions restored to R10's proven RNE f32_bf16 + residual.
//  - B-side gathers nt-pipelined (prefetch next 8 dwords during current
//    convert+MFMA) to keep live VGPRs ~114 < 128 cap at launch_bounds(512,4).
//  - everything else identical to R11: h in A-frag layout with row perm
//    e = 4*(m&3)+(m>>2); stage swizzle bijection; GRP=80/SRH=408 kf LDS pad;
//    4-term (ah,al)x(bh,bl) agg MFMA; phase-2 / prep / launcher unchanged.

namespace {
constexpr int NQ   = 50000;
constexpr int MS   = 50000;
constexpr int KNN  = 32;
constexpr int KP   = 15;
constexpr int CIN  = 64;
constexpr int COUT = 128;
constexpr int QB   = 32;                 // queries per block (2 MFMA m-tiles)
constexpr int ROWS = KP * CIN;           // 960
constexpr int RND  = 3;
constexpr int RE   = 5;                  // kernel points per round
constexpr int KBR  = (RE * CIN) / 32;    // 10
constexpr int KBT  = ROWS / 32;          // 30
constexpr int GRP  = 80;                 // shorts per 64-slot K group (16 pad)
constexpr int SRH  = 408;                // kf row stride in shorts (816 B = 51*16)
constexpr int LO_OFF = QB * SRH;         // 13056 shorts -> lo plane offset
constexpr float KP_EXT_INV = 1.0f / 1.2f;
constexpr size_t WSB_HI  = 200704;
constexpr size_t WSB_LO  = 446464;
constexpr size_t WSB_END = 692224;
}

typedef __attribute__((ext_vector_type(8))) short short8;
typedef __attribute__((ext_vector_type(4))) float f32x4;

__device__ __forceinline__ short f32_bf16(float x) {
    unsigned u = __builtin_bit_cast(unsigned, x);
    u = u + 0x7fffu + ((u >> 16) & 1u);
    return (short)(u >> 16);
}
__device__ __forceinline__ float bf16_f32(short h) {
    unsigned u = ((unsigned)(unsigned short)h) << 16;
    return __builtin_bit_cast(float, u);
}
// exact truncation split: x = bf16(hi) + r, lo = trunc-bf16(r); r computed exactly
__device__ __forceinline__ void split_trunc(float x, short& hi, short& lo) {
    unsigned u = __builtin_bit_cast(unsigned, x);
    hi = (short)(u >> 16);
    float r = x - __builtin_bit_cast(float, u & 0xffff0000u);
    lo = (short)(__builtin_bit_cast(unsigned, r) >> 16);
}

// ---- prep: W split into B-frag layout (b<60) + rowsums (b>=60) ----
__global__ __launch_bounds__(256)
void prep_basic(const float* __restrict__ s_feats, const float* __restrict__ W,
                float* __restrict__ rs, short* __restrict__ whi, short* __restrict__ wlo)
{
    int b = blockIdx.x;
    if (b < 60) {
        int wv = threadIdx.x >> 6, lane = threadIdx.x & 63;
        int id = b * 4 + wv;
        int t = id / KBT, kb = id % KBT;
        short8 hi8, lo8;
        #pragma unroll
        for (int j = 0; j < 8; ++j) {
            int row = kb * 32 + ((lane >> 4) & 3) * 8 + j;
            int col = t * 16 + (lane & 15);
            float x = W[(size_t)row * COUT + col];
            short h = f32_bf16(x);
            hi8[j] = h;
            lo8[j] = f32_bf16(x - bf16_f32(h));
        }
        ((short8*)whi)[id * 64 + lane] = hi8;
        ((short8*)wlo)[id * 64 + lane] = lo8;
    } else {
        int tdx = (b - 60) * 256 + threadIdx.x;
        int row = tdx >> 3, l8 = tdx & 7;
        if (row < MS) {
            const float4* p = (const float4*)(s_feats + (size_t)row * CIN + l8 * 8);
            float4 a = p[0], c = p[1];
            float s = ((a.x + a.y) + (a.z + a.w)) + ((c.x + c.y) + (c.z + c.w));
            s += __shfl_xor(s, 1);
            s += __shfl_xor(s, 2);
            s += __shfl_xor(s, 4);
            if (l8 == 0) rs[row] = s;
        }
    }
}

// ---- main fused kernel ----
__global__ __launch_bounds__(512, 4)
void kpconv_mfma(const float* __restrict__ q_pts,
                 const float* __restrict__ s_pts,
                 const float* __restrict__ s_feats,
                 const int*   __restrict__ neigh,
                 const float* __restrict__ kpts,
                 const float* __restrict__ rowsum,
                 const short* __restrict__ whi,
                 const short* __restrict__ wlo,
                 float*       __restrict__ out)
{
    __shared__ __align__(16) short smem_s[2 * QB * SRH];   // 52224 B (hi + lo plane)
    __shared__ float norm_s[QB];

    const int tid  = threadIdx.x;
    const int lane = tid & 63;
    const int wv   = tid >> 6;       // 0..7
    const int blk  = blockIdx.x;
    const int k32  = lane & 31;
    const int quad = lane >> 4;
    const int half = lane >> 5;
    const int c15  = lane & 15;

    // transient per-wave staging (dead before first dump sync): [8 wv][4 j][32 k]
    float4* stage = (float4*)smem_s;                       // 16 KiB of the kf region

    // per-lane kernel point for agg A-frag rows: A row m=lane&15 carries
    // e = perm(m) = 4*(m&3) + (m>>2); m==15 -> e==15 pad row (never dumped)
    const int eA = ((lane & 3) << 2) | ((lane >> 2) & 3);
    float kx, ky, kz;
    if (eA < KP) {
        kx = kpts[eA * 3 + 0]; ky = kpts[eA * 3 + 1]; kz = kpts[eA * 3 + 2];
    } else {
        kx = 1e6f; ky = 1e6f; kz = 1e6f;                   // -> pad row, never dumped
    }

    // ---------------- Phase 1 prologue: gathers + norm + LDS staging ----------------
    #pragma unroll
    for (int j = 0; j < 4; ++j) {
        const int n  = blk * QB + wv * 4 + j;
        const int nc = n < NQ ? n : NQ - 1;
        const int idx = neigh[nc * KNN + k32];
        const float qx = q_pts[nc * 3 + 0];
        const float qy = q_pts[nc * 3 + 1];
        const float qz = q_pts[nc * 3 + 2];
        const bool valid = idx < MS;
        const int  icv   = valid ? idx : MS - 1;
        const float px = s_pts[icv * 3 + 0];
        const float py = s_pts[icv * 3 + 1];
        const float pz = s_pts[icv * 3 + 2];
        const float rsv = rowsum[icv];
        float4 st;
        st.x = valid ? px - qx : 1e6f;
        st.y = valid ? py - qy : 1e6f;
        st.z = valid ? pz - qz : 1e6f;
        st.w = __int_as_float(icv);
        if (half == 0)  // lanes 0..31 hold k = k32; bijective slot swizzle
            stage[(wv * 4 + j) * 32 + (((k32 & 7) << 2) | (k32 >> 3))] = st;
        bool flag = valid && (rsv > 0.0f);
        unsigned long long bm = __ballot(flag);            // halves duplicate each k
        int cnt = (int)(__popcll(bm) >> 1);
        if (lane == 0) norm_s[wv * 4 + j] = 1.0f / (float)(cnt > 1 ? cnt : 1);
    }
    __builtin_amdgcn_wave_barrier();

    // ---------------- Phase 1 main: MFMA aggregation kf[e][c] per query ----------------
    f32x4 kfa[4][4];   // [query j][n-tile nt]; C-frag row = quad*4+reg -> e = 4*reg+quad
    #pragma unroll
    for (int j = 0; j < 4; ++j)
        #pragma unroll
        for (int nt = 0; nt < 4; ++nt)
            kfa[j][nt] = (f32x4){0.f, 0.f, 0.f, 0.f};

    const float* __restrict__ fbase = s_feats + c15;

    #pragma unroll
    for (int j = 0; j < 4; ++j) {
        // pass A: stage-read all 8 sd -> h values + feature row offsets
        float hv[8];
        int   off8[8];
        #pragma unroll
        for (int jj = 0; jj < 8; ++jj) {
            float4 sd = stage[(wv * 4 + j) * 32 + ((jj << 2) | quad)]; // k = quad*8+jj
            off8[jj] = __float_as_int(sd.w) << 6;
            float ax = sd.x - kx, ay = sd.y - ky, az = sd.z - kz;
            float d2 = ax * ax + ay * ay + az * az + 1e-8f;
            float hh = 1.0f - sqrtf(d2) * KP_EXT_INV;
            hv[jj] = hh > 0.0f ? hh : 0.0f;
        }
        // A-frag split (element jj <-> k = quad*8+jj)
        short ahs[8], als[8];
        #pragma unroll
        for (int jj = 0; jj < 8; ++jj) split_trunc(hv[jj], ahs[jj], als[jj]);
        const short8 ah = {ahs[0], ahs[1], ahs[2], ahs[3], ahs[4], ahs[5], ahs[6], ahs[7]};
        const short8 al = {als[0], als[1], als[2], als[3], als[4], als[5], als[6], als[7]};

        // B pipeline over n-tiles: gather next while converting+MFMA current
        float cur[8];
        #pragma unroll
        for (int jj = 0; jj < 8; ++jj) cur[jj] = fbase[off8[jj]];
        #pragma unroll
        for (int nt = 0; nt < 4; ++nt) {
            float nxt[8];
            if (nt < 3) {
                #pragma unroll
                for (int jj = 0; jj < 8; ++jj) nxt[jj] = fbase[off8[jj] + 16 * (nt + 1)];
            }
            short bhs[8], bls[8];
            #pragma unroll
            for (int jj = 0; jj < 8; ++jj) split_trunc(cur[jj], bhs[jj], bls[jj]);
            const short8 bh = {bhs[0], bhs[1], bhs[2], bhs[3], bhs[4], bhs[5], bhs[6], bhs[7]};
            const short8 bl = {bls[0], bls[1], bls[2], bls[3], bls[4], bls[5], bls[6], bls[7]};
            kfa[j][nt] = __builtin_amdgcn_mfma_f32_16x16x32_bf16(ah, bh, kfa[j][nt], 0, 0, 0);
            kfa[j][nt] = __builtin_amdgcn_mfma_f32_16x16x32_bf16(al, bh, kfa[j][nt], 0, 0, 0);
            kfa[j][nt] = __builtin_amdgcn_mfma_f32_16x16x32_bf16(ah, bl, kfa[j][nt], 0, 0, 0);
            kfa[j][nt] = __builtin_amdgcn_mfma_f32_16x16x32_bf16(al, bl, kfa[j][nt], 0, 0, 0);
            if (nt < 3) {
                #pragma unroll
                for (int jj = 0; jj < 8; ++jj) cur[jj] = nxt[jj];
            }
        }
    }

    // ---------------- Phase 2: split-bf16 MFMA GEMM, hi/lo LDS planes ----------------
    const short8* wh = (const short8*)whi;
    const short8* wl = (const short8*)wlo;
    f32x4 acc0 = {0.f, 0.f, 0.f, 0.f};   // m-tile 0 (queries 0..15)
    f32x4 acc1 = {0.f, 0.f, 0.f, 0.f};   // m-tile 1 (queries 16..31)
    const int qA = c15;

    #pragma unroll
    for (int r = 0; r < RND; ++r) {
        __syncthreads();
        // dump: value at (e = 4*reg+quad, c = c15+16*nt) -> round r = e/5, e5 = e%5,
        // LDS short index q*SRH + e5*GRP + c  (K slot g = e*64+c, natural order)
        #pragma unroll
        for (int j = 0; j < 4; ++j) {
            const int q = 4 * wv + j;
            #pragma unroll
            for (int reg = 0; reg < 4; ++reg) {
                const int e  = 4 * reg + quad;
                const int e5 = e - 5 * r;
                if (e5 >= 0 && e5 < RE) {
                    #pragma unroll
                    for (int nt = 0; nt < 4; ++nt) {
                        float v = kfa[j][nt][reg];
                        short hi = f32_bf16(v);
                        short lo = f32_bf16(v - bf16_f32(hi));
                        const int base = q * SRH + e5 * GRP + c15 + 16 * nt;
                        smem_s[base]          = hi;
                        smem_s[LO_OFF + base] = lo;
                    }
                }
            }
        }
        __syncthreads();

        #pragma unroll 2
        for (int kb = 0; kb < KBR; ++kb) {
            const int aoff = (kb >> 1) * GRP + (kb & 1) * 32 + quad * 8;
            short8 ah0 = *(const short8*)(smem_s + qA * SRH + aoff);
            short8 al0 = *(const short8*)(smem_s + LO_OFF + qA * SRH + aoff);
            short8 ah1 = *(const short8*)(smem_s + (16 + qA) * SRH + aoff);
            short8 al1 = *(const short8*)(smem_s + LO_OFF + (16 + qA) * SRH + aoff);

            const int kbg = r * KBR + kb;
            short8 bh = wh[(wv * KBT + kbg) * 64 + lane];
            short8 bl = wl[(wv * KBT + kbg) * 64 + lane];

            acc0 = __builtin_amdgcn_mfma_f32_16x16x32_bf16(ah0, bh, acc0, 0, 0, 0);
            acc1 = __builtin_amdgcn_mfma_f32_16x16x32_bf16(ah1, bh, acc1, 0, 0, 0);
            acc0 = __builtin_amdgcn_mfma_f32_16x16x32_bf16(ah0, bl, acc0, 0, 0, 0);
            acc1 = __builtin_amdgcn_mfma_f32_16x16x32_bf16(ah1, bl, acc1, 0, 0, 0);
            acc0 = __builtin_amdgcn_mfma_f32_16x16x32_bf16(al0, bh, acc0, 0, 0, 0);
            acc1 = __builtin_amdgcn_mfma_f32_16x16x32_bf16(al1, bh, acc1, 0, 0, 0);
        }
    }

    // epilogue: D row m = quad*4+rr (query within tile), col = lane&15
    const int oc = c15;
    #pragma unroll
    for (int rr = 0; rr < 4; ++rr) {
        int qm0 = quad * 4 + rr;
        int qm1 = 16 + qm0;
        int n0 = blk * QB + qm0;
        int n1 = blk * QB + qm1;
        if (n0 < NQ) out[(size_t)n0 * COUT + wv * 16 + oc] = acc0[rr] * norm_s[qm0];
        if (n1 < NQ) out[(size_t)n1 * COUT + wv * 16 + oc] = acc1[rr] * norm_s[qm1];
    }
}

// ---- fallback (no workspace; R2-verified structure) ----
__global__ __launch_bounds__(256, 6)
void kpconv_fallback(const float* __restrict__ q_pts,
                     const float* __restrict__ s_pts,
                     const float* __restrict__ s_feats,
                     const int*   __restrict__ neigh,
                     const float* __restrict__ W,
                     const float* __restrict__ kpts,
                     float*       __restrict__ out)
{
    constexpr int QBF = 16, CHUNK_I = 320, NPAIR = 160;
    __shared__ __align__(16) float smem[NPAIR * 32];
    __shared__ float norm_s[QBF];
    float (*h_lds)[KNN][20] = (float (*)[KNN][20])smem;
    float (*dxyz)[KNN][3]   = (float (*)[KNN][3])(smem + 2560);
    int*   idxl             = (int*)(smem + 2944);
    float* kp_s             = smem + 3072;

    const int tid = threadIdx.x, lane = tid & 63, wv = tid >> 6, blk = blockIdx.x;
    const int k32 = lane & 31, half = lane >> 5;
    if (tid < KP * 3) kp_s[tid] = kpts[tid];
    __syncthreads();
    float kfv[4][KP];

    #pragma unroll
    for (int j = 0; j < 4; ++j) {
        const int q = wv * 4 + j, n = blk * QBF + q;
        const float qx = q_pts[n*3], qy = q_pts[n*3+1], qz = q_pts[n*3+2];
        if (lane < KNN) {
            int idx = neigh[n * KNN + k32];
            idxl[wv * KNN + k32] = idx;
            bool valid = idx < MS;
            int ic = valid ? idx : MS - 1;
            dxyz[wv][k32][0] = valid ? s_pts[ic*3]   - qx : 1e6f;
            dxyz[wv][k32][1] = valid ? s_pts[ic*3+1] - qy : 1e6f;
            dxyz[wv][k32][2] = valid ? s_pts[ic*3+2] - qz : 1e6f;
        }
        __builtin_amdgcn_wave_barrier();
        const float dx = dxyz[wv][k32][0], dy = dxyz[wv][k32][1], dz = dxyz[wv][k32][2];
        float om = 0.0f;
        #pragma unroll
        for (int p = 0; p < 8; ++p) {
            const int e = (p << 1) + half;
            if (e < KP) {
                float ax = dx - kp_s[e*3], ay = dy - kp_s[e*3+1], az = dz - kp_s[e*3+2];
                float hh = 1.0f - sqrtf(ax*ax + ay*ay + az*az + 1e-8f) * KP_EXT_INV;
                hh = hh > 0.0f ? hh : 0.0f;
                h_lds[wv][k32][e] = hh;
                om = fmaxf(om, hh);
            }
        }
        om = fmaxf(om, __shfl_xor(om, 32));
        unsigned int kmask = (unsigned int)__ballot(om > 0.0f);
        __builtin_amdgcn_wave_barrier();
        {
            int idx = idxl[wv * KNN + k32];
            bool valid = idx < MS;
            int ic = valid ? idx : MS - 1;
            const float4* rp = (const float4*)(s_feats + (size_t)ic * CIN + half * 32);
            float4 s4 = rp[0];
            #pragma unroll
            for (int t = 1; t < 8; ++t) { float4 a = rp[t]; s4.x+=a.x; s4.y+=a.y; s4.z+=a.z; s4.w+=a.w; }
            float s = (s4.x + s4.y) + (s4.z + s4.w);
            s += __shfl_xor(s, 32);
            unsigned long long b = __ballot(valid && (s > 0.0f));
            int cnt = (int)(__popcll(b) >> 1);
            if (lane == 0) norm_s[q] = 1.0f / (float)(cnt > 1 ? cnt : 1);
        }
        #pragma unroll
        for (int e = 0; e < KP; ++e) kfv[j][e] = 0.0f;
        unsigned int mk = kmask;
        while (mk) {
            int k = __builtin_ctz(mk); mk &= mk - 1;
            int idx2 = idxl[wv * KNN + k];
            int ic2 = idx2 < MS ? idx2 : MS - 1;
            float nf = s_feats[(size_t)ic2 * CIN + lane];
            const float4* hr = (const float4*)(&h_lds[wv][k][0]);
            float4 h0 = hr[0], h1 = hr[1], h2 = hr[2], h3 = hr[3];
            kfv[j][0]+=h0.x*nf; kfv[j][1]+=h0.y*nf; kfv[j][2]+=h0.z*nf; kfv[j][3]+=h0.w*nf;
            kfv[j][4]+=h1.x*nf; kfv[j][5]+=h1.y*nf; kfv[j][6]+=h1.z*nf; kfv[j][7]+=h1.w*nf;
            kfv[j][8]+=h2.x*nf; kfv[j][9]+=h2.y*nf; kfv[j][10]+=h2.z*nf; kfv[j][11]+=h2.w*nf;
            kfv[j][12]+=h3.x*nf; kfv[j][13]+=h3.y*nf; kfv[j][14]+=h3.z*nf;
        }
    }

    const int o4 = tid & 31, qi = tid >> 5, q0 = qi * 2, q1 = q0 + 1;
    float4 tot0 = make_float4(0,0,0,0), tot1 = make_float4(0,0,0,0);
    #pragma unroll
    for (int r = 0; r < 3; ++r) {
        __syncthreads();
        #pragma unroll
        for (int j = 0; j < 4; ++j) {
            const int q = wv * 4 + j;
            #pragma unroll
            for (int e5 = 0; e5 < 5; ++e5) {
                int i = e5 * CIN + lane, pr = i >> 1, m = pr & 14;
                smem[pr * 32 + ((q ^ m) << 1) + (i & 1)] = kfv[j][r * 5 + e5];
            }
        }
        __syncthreads();
        const float* wb = W + (size_t)(r * CHUNK_I) * COUT + (o4 << 2);
        float4 acc0 = make_float4(0,0,0,0), acc1 = make_float4(0,0,0,0);
        #pragma unroll 4
        for (int p = 0; p < NPAIR; ++p) {
            float4 kk = *(const float4*)(smem + p * 32 + ((q0 ^ (p & 14)) << 1));
            float4 w0 = *(const float4*)(wb + (size_t)(2*p) * COUT);
            float4 w1 = *(const float4*)(wb + (size_t)(2*p+1) * COUT);
            acc0.x+=w0.x*kk.x; acc0.y+=w0.y*kk.x; acc0.z+=w0.z*kk.x; acc0.w+=w0.w*kk.x;
            acc1.x+=w0.x*kk.z; acc1.y+=w0.y*kk.z; acc1.z+=w0.z*kk.z; acc1.w+=w0.w*kk.z;
            acc0.x+=w1.x*kk.y; acc0.y+=w1.y*kk.y; acc0.z+=w1.z*kk.y; acc0.w+=w1.w*kk.y;
            acc1.x+=w1.x*kk.w; acc1.y+=w1.y*kk.w; acc1.z+=w1.z*kk.w; acc1.w+=w1.w*kk.w;
        }
        tot0.x+=acc0.x; tot0.y+=acc0.y; tot0.z+=acc0.z; tot0.w+=acc0.w;
        tot1.x+=acc1.x; tot1.y+=acc1.y; tot1.z+=acc1.z; tot1.w+=acc1.w;
    }
    const float nm0 = norm_s[q0], nm1 = norm_s[q1];
    const size_t base = (size_t)(blk * QBF) * COUT + (o4 << 2);
    *(float4*)(out + base + (size_t)q0 * COUT) =
        make_float4(tot0.x*nm0, tot0.y*nm0, tot0.z*nm0, tot0.w*nm0);
    *(float4*)(out + base + (size_t)q1 * COUT) =
        make_float4(tot1.x*nm1, tot1.y*nm1, tot1.z*nm1, tot1.w*nm1);
}

extern "C" void kernel_launch(void* const* d_in, const int* in_sizes, int n_in,
                              void* d_out, int out_size, void* d_ws, size_t ws_size,
                              hipStream_t stream) {
    const float* q_pts   = (const float*)d_in[0];
    const float* s_pts   = (const float*)d_in[1];
    const float* s_feats = (const float*)d_in[2];
    const int*   neigh   = (const int*)d_in[3];
    const float* W       = (const float*)d_in[4];
    const float* kpts    = (const float*)d_in[5];
    float* outp = (float*)d_out;

    dim3 mgrid((NQ + QB - 1) / QB);   // 1563
    dim3 mblock(512);

    if (ws_size >= WSB_END) {
        float* rs  = (float*)d_ws;
        short* whi = (short*)((char*)d_ws + WSB_HI);
        short* wlo = (short*)((char*)d_ws + WSB_LO);
        int rs_blocks = (MS * 8 + 255) / 256;
        hipLaunchKernelGGL(prep_basic, dim3(60 + rs_blocks), dim3(256), 0, stream,
                           s_feats, W, rs, whi, wlo);
        hipLaunchKernelGGL(kpconv_mfma, mgrid, mblock, 0, stream,
                           q_pts, s_pts, s_feats, neigh, kpts, rs, whi, wlo, outp);
    } else {
        hipLaunchKernelGGL(kpconv_fallback, dim3(NQ / 16), dim3(256), 0, stream,
                           q_pts, s_pts, s_feats, neigh, W, kpts, outp);
    }
}

// Round 3
// 157.744 us; speedup vs baseline: 1.2135x; 1.2135x over previous
//
#include <hip/hip_runtime.h>

// KPConv fused, R13 = exact R10 revert (85us verified; R11/R12's MFMA-agg
// regressed FETCH 9MB->176MB via per-lane scatter gather) + e-sparsity skip:
//  - geometry: P((k,e) live) ~0.058 -> live slots average ~1.5 nonzero e of 15;
//    R10's 15-fma inner loop multiplies by exact zero ~90% of the time.
//  - h-compute now also builds a per-slot 15-bit liveness mask (emask), both
//    halves OR'd via shfl_xor(32); compaction stores it to cem[] (LDS, dead
//    region above kp_s) alongside cpk[].
//  - slot loop restructured e-outer: per 4-slot batch, union mask emU (SGPRs,
//    readfirstlane'd) guards each e's 4x(readlane+fmac) group with a
//    wave-uniform branch -> ~10 of 15 e-groups skipped per batch. Skipped work
//    is exact no-ops (h==0), results bit-identical.
//  - everything else verbatim R10: prologue gathers, 2-deep pipelined batch-4
//    slot loop, split-bf16 hi/lo LDS planes (SRH=328), phase-2 GEMM, epilogue.

namespace {
constexpr int NQ   = 50000;
constexpr int MS   = 50000;
constexpr int KNN  = 32;
constexpr int KP   = 15;
constexpr int CIN  = 64;
constexpr int COUT = 128;
constexpr int QB   = 32;                 // queries per block (2 MFMA m-tiles)
constexpr int ROWS = KP * CIN;           // 960
constexpr int RND  = 3;
constexpr int RE   = 5;                  // kernel points per round
constexpr int KBR  = (RE * CIN) / 32;    // 10
constexpr int KBT  = ROWS / 32;          // 30
constexpr int SRH  = 328;                // kf row stride in shorts (656 B = 41*16)
constexpr int LO_OFF = QB * SRH;         // 10496 shorts -> lo plane offset
constexpr float KP_EXT_INV = 1.0f / 1.2f;
constexpr int OF_CPK = 0;                // 8 waves * 32 ints (overlaps kf rows; dead by dump)
constexpr int OF_KP  = 256;              // 45 floats
constexpr int OF_CEM = 304;              // 8 waves * 32 ints (emask; dead by dump)
constexpr size_t WSB_HI  = 200704;
constexpr size_t WSB_LO  = 446464;
constexpr size_t WSB_END = 692224;
}

typedef __attribute__((ext_vector_type(8))) short short8;
typedef __attribute__((ext_vector_type(4))) float f32x4;

__device__ __forceinline__ short f32_bf16(float x) {
    unsigned u = __builtin_bit_cast(unsigned, x);
    u = u + 0x7fffu + ((u >> 16) & 1u);
    return (short)(u >> 16);
}
__device__ __forceinline__ float bf16_f32(short h) {
    unsigned u = ((unsigned)(unsigned short)h) << 16;
    return __builtin_bit_cast(float, u);
}
__device__ __forceinline__ float readlane_f(float v, int l) {
    return __builtin_bit_cast(float,
        __builtin_amdgcn_readlane(__builtin_bit_cast(int, v), l));
}

// ---- prep: W split into B-frag layout (b<60) + rowsums (b>=60) ----
__global__ __launch_bounds__(256)
void prep_basic(const float* __restrict__ s_feats, const float* __restrict__ W,
                float* __restrict__ rs, short* __restrict__ whi, short* __restrict__ wlo)
{
    int b = blockIdx.x;
    if (b < 60) {
        int wv = threadIdx.x >> 6, lane = threadIdx.x & 63;
        int id = b * 4 + wv;
        int t = id / KBT, kb = id % KBT;
        short8 hi8, lo8;
        #pragma unroll
        for (int j = 0; j < 8; ++j) {
            int row = kb * 32 + ((lane >> 4) & 3) * 8 + j;
            int col = t * 16 + (lane & 15);
            float x = W[(size_t)row * COUT + col];
            short h = f32_bf16(x);
            hi8[j] = h;
            lo8[j] = f32_bf16(x - bf16_f32(h));
        }
        ((short8*)whi)[id * 64 + lane] = hi8;
        ((short8*)wlo)[id * 64 + lane] = lo8;
    } else {
        int tdx = (b - 60) * 256 + threadIdx.x;
        int row = tdx >> 3, l8 = tdx & 7;
        if (row < MS) {
            const float4* p = (const float4*)(s_feats + (size_t)row * CIN + l8 * 8);
            float4 a = p[0], c = p[1];
            float s = ((a.x + a.y) + (a.z + a.w)) + ((c.x + c.y) + (c.z + c.w));
            s += __shfl_xor(s, 1);
            s += __shfl_xor(s, 2);
            s += __shfl_xor(s, 4);
            if (l8 == 0) rs[row] = s;
        }
    }
}

// ---- main fused kernel ----
__global__ __launch_bounds__(512, 4)
void kpconv_mfma(const float* __restrict__ q_pts,
                 const float* __restrict__ s_pts,
                 const float* __restrict__ s_feats,
                 const int*   __restrict__ neigh,
                 const float* __restrict__ kpts,
                 const float* __restrict__ rowsum,
                 const short* __restrict__ whi,
                 const short* __restrict__ wlo,
                 float*       __restrict__ out)
{
    __shared__ __align__(16) short smem_s[2 * QB * SRH];   // 41984 B (hi plane + lo plane)
    __shared__ float norm_s[QB];

    float* smf = (float*)smem_s;
    const int tid  = threadIdx.x;
    const int lane = tid & 63;
    const int wv   = tid >> 6;       // 0..7
    const int blk  = blockIdx.x;
    const int k32  = lane & 31;
    const int quad = lane >> 4;
    const int half = lane >> 5;
    const int c15  = lane & 15;

    int*   cpk  = (int*)(smf + OF_CPK) + wv * 32;   // overlaps kf rows; dead before dump
    float* kp_s = smf + OF_KP;
    int*   cem  = (int*)(smf + OF_CEM) + wv * 32;   // per-slot e-liveness masks

    if (tid < KP * 3) kp_s[tid] = kpts[tid];
    __syncthreads();

    float kfv[4][KP];   // scalar accumulators (AGPR-friendly; do NOT vectorize)

    // ---------------- Phase 1 prologue: all 4 queries' gathers in flight ----------------
    float dxa[4], dya[4], dza[4];
    int   idxa[4];
    {
        int nca[4];
        #pragma unroll
        for (int j = 0; j < 4; ++j) {
            const int n = blk * QB + wv * 4 + j;
            nca[j] = n < NQ ? n : NQ - 1;
        }
        #pragma unroll
        for (int j = 0; j < 4; ++j) idxa[j] = neigh[nca[j] * KNN + k32];
        #pragma unroll
        for (int j = 0; j < 4; ++j) {
            const float qx = q_pts[nca[j] * 3 + 0];
            const float qy = q_pts[nca[j] * 3 + 1];
            const float qz = q_pts[nca[j] * 3 + 2];
            bool valid = idxa[j] < MS;
            int  icv   = valid ? idxa[j] : MS - 1;
            float px = s_pts[icv * 3 + 0];
            float py = s_pts[icv * 3 + 1];
            float pz = s_pts[icv * 3 + 2];
            float rsv = rowsum[icv];
            dxa[j] = valid ? px - qx : 1e6f;
            dya[j] = valid ? py - qy : 1e6f;
            dza[j] = valid ? pz - qz : 1e6f;
            bool flag = valid && (rsv > 0.0f);
            unsigned long long b = __ballot(flag);      // halves duplicate each k
            int cnt = (int)(__popcll(b) >> 1);
            if (lane == 0) norm_s[wv * 4 + j] = 1.0f / (float)(cnt > 1 ? cnt : 1);
        }
    }

    // ---------------- Phase 1 main: per-query h + aggregation ----------------
    #pragma unroll
    for (int j = 0; j < 4; ++j) {
        const float dx = dxa[j], dy = dya[j], dz = dza[j];
        const int idxv = idxa[j];

        // 1b: h[k][e] in registers; lane (k32,half) holds e = 2p+half in hreg[p]
        float hreg[8];
        unsigned em = 0;
        #pragma unroll
        for (int p = 0; p < 8; ++p) {
            const int e = (p << 1) + half;
            float hh = 0.0f;
            if (e < KP) {
                float ax = dx - kp_s[e * 3 + 0];
                float ay = dy - kp_s[e * 3 + 1];
                float az = dz - kp_s[e * 3 + 2];
                float d2 = ax * ax + ay * ay + az * az + 1e-8f;
                hh = 1.0f - sqrtf(d2) * KP_EXT_INV;
                hh = hh > 0.0f ? hh : 0.0f;
            }
            hreg[p] = hh;
            em |= (hh > 0.0f ? 1u : 0u) << e;
        }
        em |= (unsigned)__shfl_xor((int)em, 32);        // both halves' e-bits
        unsigned int kmask = (unsigned int)__ballot(em != 0);  // low 32 = per-k live
        const int nv = __popc(kmask);

        // compaction: slot -> (row<<6)|k for live, 0 for pads; emask alongside
        if (lane < KNN) {
            bool bit = (kmask >> k32) & 1u;
            unsigned lm = (1u << k32) - 1u;
            int pos = bit ? __popc(kmask & lm) : nv + __popc((~kmask) & lm);
            cpk[pos] = bit ? ((idxv << 6) | k32) : 0;
            cem[pos] = bit ? (int)em : 0;
        }
        __builtin_amdgcn_wave_barrier();

        #pragma unroll
        for (int e = 0; e < KP; ++e) kfv[j][e] = 0.0f;

        // 2-deep pipelined batch-4 slot loop (R8 granularity, prefetch next)
        const int nvr = (nv + 3) & ~3;
        int   pkc[4], emc[4];
        float nfc[4];
        #pragma unroll
        for (int u = 0; u < 4; ++u) {
            pkc[u] = __builtin_amdgcn_readfirstlane(cpk[u]);
            emc[u] = __builtin_amdgcn_readfirstlane(cem[u]);
        }
        #pragma unroll
        for (int u = 0; u < 4; ++u) nfc[u] = s_feats[(size_t)(pkc[u] >> 6) * CIN + lane];

        for (int base = 0; base < nvr; base += 4) {
            int   pkn[4], emn[4];
            float nfn[4];
            #pragma unroll
            for (int u = 0; u < 4; ++u) {
                int ii = base + 4 + u;
                ii = ii < 31 ? ii : 31;          // in-bounds; pads hold 0 (safe)
                pkn[u] = __builtin_amdgcn_readfirstlane(cpk[ii]);
                emn[u] = __builtin_amdgcn_readfirstlane(cem[ii]);
            }
            #pragma unroll
            for (int u = 0; u < 4; ++u) nfn[u] = s_feats[(size_t)(pkn[u] >> 6) * CIN + lane];

            // hoist per-slot f (pad-masked) and lane base
            float fs[4];
            int   kks[4];
            #pragma unroll
            for (int u = 0; u < 4; ++u) {
                fs[u]  = (base + u < nv) ? nfc[u] : 0.0f;
                kks[u] = pkc[u] & 63;
            }
            // union e-mask over the batch (SGPRs); skip dead e-groups wave-uniformly
            const unsigned emU = (unsigned)(emc[0] | emc[1] | emc[2] | emc[3]);
            #pragma unroll
            for (int e = 0; e < KP; ++e) {
                if ((emU >> e) & 1u) {
                    #pragma unroll
                    for (int u = 0; u < 4; ++u) {
                        float he = readlane_f(hreg[e >> 1], kks[u] | ((e & 1) << 5));
                        kfv[j][e] += he * fs[u];
                    }
                }
            }
            #pragma unroll
            for (int u = 0; u < 4; ++u) { pkc[u] = pkn[u]; nfc[u] = nfn[u]; emc[u] = emn[u]; }
        }
    }

    // ---------------- Phase 2: split-bf16 MFMA GEMM, hi/lo LDS planes ----------------
    const short8* wh = (const short8*)whi;
    const short8* wl = (const short8*)wlo;
    f32x4 acc0 = {0.f, 0.f, 0.f, 0.f};   // m-tile 0 (queries 0..15)
    f32x4 acc1 = {0.f, 0.f, 0.f, 0.f};   // m-tile 1 (queries 16..31)
    const int qA = c15;

    #pragma unroll
    for (int r = 0; r < RND; ++r) {
        __syncthreads();
        // dump: row q, element i = e5*64 + lane; hi plane + lo plane (ds_write_b16)
        #pragma unroll
        for (int j = 0; j < 4; ++j) {
            const int q = 4 * wv + j;
            #pragma unroll
            for (int e5 = 0; e5 < RE; ++e5) {
                float v  = kfv[j][r * RE + e5];
                short hi = f32_bf16(v);
                short lo = f32_bf16(v - bf16_f32(hi));
                smem_s[q * SRH + e5 * 64 + lane]          = hi;
                smem_s[LO_OFF + q * SRH + e5 * 64 + lane] = lo;
            }
        }
        __syncthreads();

        #pragma unroll 2
        for (int kb = 0; kb < KBR; ++kb) {
            const int ai = kb * 32 + quad * 8;
            short8 ah0 = *(const short8*)(smem_s + qA * SRH + ai);
            short8 al0 = *(const short8*)(smem_s + LO_OFF + qA * SRH + ai);
            short8 ah1 = *(const short8*)(smem_s + (16 + qA) * SRH + ai);
            short8 al1 = *(const short8*)(smem_s + LO_OFF + (16 + qA) * SRH + ai);

            const int kbg = r * KBR + kb;
            short8 bh = wh[(wv * KBT + kbg) * 64 + lane];
            short8 bl = wl[(wv * KBT + kbg) * 64 + lane];

            acc0 = __builtin_amdgcn_mfma_f32_16x16x32_bf16(ah0, bh, acc0, 0, 0, 0);
            acc1 = __builtin_amdgcn_mfma_f32_16x16x32_bf16(ah1, bh, acc1, 0, 0, 0);
            acc0 = __builtin_amdgcn_mfma_f32_16x16x32_bf16(ah0, bl, acc0, 0, 0, 0);
            acc1 = __builtin_amdgcn_mfma_f32_16x16x32_bf16(ah1, bl, acc1, 0, 0, 0);
            acc0 = __builtin_amdgcn_mfma_f32_16x16x32_bf16(al0, bh, acc0, 0, 0, 0);
            acc1 = __builtin_amdgcn_mfma_f32_16x16x32_bf16(al1, bh, acc1, 0, 0, 0);
        }
    }

    // epilogue: D row m = quad*4+rr (query within tile), col = lane&15
    const int oc = c15;
    #pragma unroll
    for (int rr = 0; rr < 4; ++rr) {
        int qm0 = quad * 4 + rr;
        int qm1 = 16 + qm0;
        int n0 = blk * QB + qm0;
        int n1 = blk * QB + qm1;
        if (n0 < NQ) out[(size_t)n0 * COUT + wv * 16 + oc] = acc0[rr] * norm_s[qm0];
        if (n1 < NQ) out[(size_t)n1 * COUT + wv * 16 + oc] = acc1[rr] * norm_s[qm1];
    }
}

// ---- fallback (no workspace; R2-verified structure) ----
__global__ __launch_bounds__(256, 6)
void kpconv_fallback(const float* __restrict__ q_pts,
                     const float* __restrict__ s_pts,
                     const float* __restrict__ s_feats,
                     const int*   __restrict__ neigh,
                     const float* __restrict__ W,
                     const float* __restrict__ kpts,
                     float*       __restrict__ out)
{
    constexpr int QBF = 16, CHUNK_I = 320, NPAIR = 160;
    __shared__ __align__(16) float smem[NPAIR * 32];
    __shared__ float norm_s[QBF];
    float (*h_lds)[KNN][20] = (float (*)[KNN][20])smem;
    float (*dxyz)[KNN][3]   = (float (*)[KNN][3])(smem + 2560);
    int*   idxl             = (int*)(smem + 2944);
    float* kp_s             = smem + 3072;

    const int tid = threadIdx.x, lane = tid & 63, wv = tid >> 6, blk = blockIdx.x;
    const int k32 = lane & 31, half = lane >> 5;
    if (tid < KP * 3) kp_s[tid] = kpts[tid];
    __syncthreads();
    float kfv[4][KP];

    #pragma unroll
    for (int j = 0; j < 4; ++j) {
        const int q = wv * 4 + j, n = blk * QBF + q;
        const float qx = q_pts[n*3], qy = q_pts[n*3+1], qz = q_pts[n*3+2];
        if (lane < KNN) {
            int idx = neigh[n * KNN + k32];
            idxl[wv * KNN + k32] = idx;
            bool valid = idx < MS;
            int ic = valid ? idx : MS - 1;
            dxyz[wv][k32][0] = valid ? s_pts[ic*3]   - qx : 1e6f;
            dxyz[wv][k32][1] = valid ? s_pts[ic*3+1] - qy : 1e6f;
            dxyz[wv][k32][2] = valid ? s_pts[ic*3+2] - qz : 1e6f;
        }
        __builtin_amdgcn_wave_barrier();
        const float dx = dxyz[wv][k32][0], dy = dxyz[wv][k32][1], dz = dxyz[wv][k32][2];
        float om = 0.0f;
        #pragma unroll
        for (int p = 0; p < 8; ++p) {
            const int e = (p << 1) + half;
            if (e < KP) {
                float ax = dx - kp_s[e*3], ay = dy - kp_s[e*3+1], az = dz - kp_s[e*3+2];
                float hh = 1.0f - sqrtf(ax*ax + ay*ay + az*az + 1e-8f) * KP_EXT_INV;
                hh = hh > 0.0f ? hh : 0.0f;
                h_lds[wv][k32][e] = hh;
                om = fmaxf(om, hh);
            }
        }
        om = fmaxf(om, __shfl_xor(om, 32));
        unsigned int kmask = (unsigned int)__ballot(om > 0.0f);
        __builtin_amdgcn_wave_barrier();
        {
            int idx = idxl[wv * KNN + k32];
            bool valid = idx < MS;
            int ic = valid ? idx : MS - 1;
            const float4* rp = (const float4*)(s_feats + (size_t)ic * CIN + half * 32);
            float4 s4 = rp[0];
            #pragma unroll
            for (int t = 1; t < 8; ++t) { float4 a = rp[t]; s4.x+=a.x; s4.y+=a.y; s4.z+=a.z; s4.w+=a.w; }
            float s = (s4.x + s4.y) + (s4.z + s4.w);
            s += __shfl_xor(s, 32);
            unsigned long long b = __ballot(valid && (s > 0.0f));
            int cnt = (int)(__popcll(b) >> 1);
            if (lane == 0) norm_s[q] = 1.0f / (float)(cnt > 1 ? cnt : 1);
        }
        #pragma unroll
        for (int e = 0; e < KP; ++e) kfv[j][e] = 0.0f;
        unsigned int mk = kmask;
        while (mk) {
            int k = __builtin_ctz(mk); mk &= mk - 1;
            int idx2 = idxl[wv * KNN + k];
            int ic2 = idx2 < MS ? idx2 : MS - 1;
            float nf = s_feats[(size_t)ic2 * CIN + lane];
            const float4* hr = (const float4*)(&h_lds[wv][k][0]);
            float4 h0 = hr[0], h1 = hr[1], h2 = hr[2], h3 = hr[3];
            kfv[j][0]+=h0.x*nf; kfv[j][1]+=h0.y*nf; kfv[j][2]+=h0.z*nf; kfv[j][3]+=h0.w*nf;
            kfv[j][4]+=h1.x*nf; kfv[j][5]+=h1.y*nf; kfv[j][6]+=h1.z*nf; kfv[j][7]+=h1.w*nf;
            kfv[j][8]+=h2.x*nf; kfv[j][9]+=h2.y*nf; kfv[j][10]+=h2.z*nf; kfv[j][11]+=h2.w*nf;
            kfv[j][12]+=h3.x*nf; kfv[j][13]+=h3.y*nf; kfv[j][14]+=h3.z*nf;
        }
    }

    const int o4 = tid & 31, qi = tid >> 5, q0 = qi * 2, q1 = q0 + 1;
    float4 tot0 = make_float4(0,0,0,0), tot1 = make_float4(0,0,0,0);
    #pragma unroll
    for (int r = 0; r < 3; ++r) {
        __syncthreads();
        #pragma unroll
        for (int j = 0; j < 4; ++j) {
            const int q = wv * 4 + j;
            #pragma unroll
            for (int e5 = 0; e5 < 5; ++e5) {
                int i = e5 * CIN + lane, pr = i >> 1, m = pr & 14;
                smem[pr * 32 + ((q ^ m) << 1) + (i & 1)] = kfv[j][r * 5 + e5];
            }
        }
        __syncthreads();
        const float* wb = W + (size_t)(r * CHUNK_I) * COUT + (o4 << 2);
        float4 acc0 = make_float4(0,0,0,0), acc1 = make_float4(0,0,0,0);
        #pragma unroll 4
        for (int p = 0; p < NPAIR; ++p) {
            float4 kk = *(const float4*)(smem + p * 32 + ((q0 ^ (p & 14)) << 1));
            float4 w0 = *(const float4*)(wb + (size_t)(2*p) * COUT);
            float4 w1 = *(const float4*)(wb + (size_t)(2*p+1) * COUT);
            acc0.x+=w0.x*kk.x; acc0.y+=w0.y*kk.x; acc0.z+=w0.z*kk.x; acc0.w+=w0.w*kk.x;
            acc1.x+=w0.x*kk.z; acc1.y+=w0.y*kk.z; acc1.z+=w0.z*kk.z; acc1.w+=w0.w*kk.z;
            acc0.x+=w1.x*kk.y; acc0.y+=w1.y*kk.y; acc0.z+=w1.z*kk.y; acc0.w+=w1.w*kk.y;
            acc1.x+=w1.x*kk.w; acc1.y+=w1.y*kk.w; acc1.z+=w1.z*kk.w; acc1.w+=w1.w*kk.w;
        }
        tot0.x+=acc0.x; tot0.y+=acc0.y; tot0.z+=acc0.z; tot0.w+=acc0.w;
        tot1.x+=acc1.x; tot1.y+=acc1.y; tot1.z+=acc1.z; tot1.w+=acc1.w;
    }
    const float nm0 = norm_s[q0], nm1 = norm_s[q1];
    const size_t base = (size_t)(blk * QBF) * COUT + (o4 << 2);
    *(float4*)(out + base + (size_t)q0 * COUT) =
        make_float4(tot0.x*nm0, tot0.y*nm0, tot0.z*nm0, tot0.w*nm0);
    *(float4*)(out + base + (size_t)q1 * COUT) =
        make_float4(tot1.x*nm1, tot1.y*nm1, tot1.z*nm1, tot1.w*nm1);
}

extern "C" void kernel_launch(void* const* d_in, const int* in_sizes, int n_in,
                              void* d_out, int out_size, void* d_ws, size_t ws_size,
                              hipStream_t stream) {
    const float* q_pts   = (const float*)d_in[0];
    const float* s_pts   = (const float*)d_in[1];
    const float* s_feats = (const float*)d_in[2];
    const int*   neigh   = (const int*)d_in[3];
    const float* W       = (const float*)d_in[4];
    const float* kpts    = (const float*)d_in[5];
    float* outp = (float*)d_out;

    dim3 mgrid((NQ + QB - 1) / QB);   // 1563
    dim3 mblock(512);

    if (ws_size >= WSB_END) {
        float* rs  = (float*)d_ws;
        short* whi = (short*)((char*)d_ws + WSB_HI);
        short* wlo = (short*)((char*)d_ws + WSB_LO);
        int rs_blocks = (MS * 8 + 255) / 256;
        hipLaunchKernelGGL(prep_basic, dim3(60 + rs_blocks), dim3(256), 0, stream,
                           s_feats, W, rs, whi, wlo);
        hipLaunchKernelGGL(kpconv_mfma, mgrid, mblock, 0, stream,
                           q_pts, s_pts, s_feats, neigh, kpts, rs, whi, wlo, outp);
    } else {
        hipLaunchKernelGGL(kpconv_fallback, dim3(NQ / 16), dim3(256), 0, stream,
                           q_pts, s_pts, s_feats, neigh, W, kpts, outp);
    }
}

// Round 4
// 150.876 us; speedup vs baseline: 1.2688x; 1.0455x over previous
//
#include <hip/hip_runtime.h>

// KPConv fused, R14 = R10 skeleton, occupancy-targeted restructure:
//  - Diagnosis: combined VGPR+AGPR ~116 (kfv[4][15]=60 AGPR) caps occupancy at
//    4 waves/SIMD (16/CU); measured 35%, no pipe saturated -> latency-bound.
//  - Round-interleaved phase-1: per round r, slot loop accumulates ONLY that
//    round's 5 kernel points (kfv5[4][5] = 20 AGPR), then dump + GEMM round.
//    Combined regs ~85-90 -> 5 waves/SIMD; __launch_bounds__(512,5).
//  - Liveness mask + compaction computed ONCE in prologue; cpk parked in
//    dedicated LDS (survives dumps). kp in dedicated LDS too (old overlay
//    region is clobbered by round-0 dump under the new schedule).
//  - Per-round h recompute: only the 3 hreg pairs covering e in [5r,5r+5).
//  - f rows re-gathered per round (3x, L2/L3-resident; issue-cheap).
//  - R13's e-skip dropped (measured exactly neutral - compiler flattened it).
//  - Phase-2 GEMM / dump / epilogue / prep / launcher verbatim R10.

namespace {
constexpr int NQ   = 50000;
constexpr int MS   = 50000;
constexpr int KNN  = 32;
constexpr int KP   = 15;
constexpr int CIN  = 64;
constexpr int COUT = 128;
constexpr int QB   = 32;                 // queries per block (2 MFMA m-tiles)
constexpr int ROWS = KP * CIN;           // 960
constexpr int RND  = 3;
constexpr int RE   = 5;                  // kernel points per round
constexpr int KBR  = (RE * CIN) / 32;    // 10
constexpr int KBT  = ROWS / 32;          // 30
constexpr int SRH  = 328;                // kf row stride in shorts (656 B = 41*16)
constexpr int LO_OFF = QB * SRH;         // 10496 shorts -> lo plane offset
constexpr float KP_EXT_INV = 1.0f / 1.2f;
constexpr size_t WSB_HI  = 200704;
constexpr size_t WSB_LO  = 446464;
constexpr size_t WSB_END = 692224;
}

typedef __attribute__((ext_vector_type(8))) short short8;
typedef __attribute__((ext_vector_type(4))) float f32x4;

__device__ __forceinline__ short f32_bf16(float x) {
    unsigned u = __builtin_bit_cast(unsigned, x);
    u = u + 0x7fffu + ((u >> 16) & 1u);
    return (short)(u >> 16);
}
__device__ __forceinline__ float bf16_f32(short h) {
    unsigned u = ((unsigned)(unsigned short)h) << 16;
    return __builtin_bit_cast(float, u);
}
__device__ __forceinline__ float readlane_f(float v, int l) {
    return __builtin_bit_cast(float,
        __builtin_amdgcn_readlane(__builtin_bit_cast(int, v), l));
}

// ---- prep: W split into B-frag layout (b<60) + rowsums (b>=60) ----
__global__ __launch_bounds__(256)
void prep_basic(const float* __restrict__ s_feats, const float* __restrict__ W,
                float* __restrict__ rs, short* __restrict__ whi, short* __restrict__ wlo)
{
    int b = blockIdx.x;
    if (b < 60) {
        int wv = threadIdx.x >> 6, lane = threadIdx.x & 63;
        int id = b * 4 + wv;
        int t = id / KBT, kb = id % KBT;
        short8 hi8, lo8;
        #pragma unroll
        for (int j = 0; j < 8; ++j) {
            int row = kb * 32 + ((lane >> 4) & 3) * 8 + j;
            int col = t * 16 + (lane & 15);
            float x = W[(size_t)row * COUT + col];
            short h = f32_bf16(x);
            hi8[j] = h;
            lo8[j] = f32_bf16(x - bf16_f32(h));
        }
        ((short8*)whi)[id * 64 + lane] = hi8;
        ((short8*)wlo)[id * 64 + lane] = lo8;
    } else {
        int tdx = (b - 60) * 256 + threadIdx.x;
        int row = tdx >> 3, l8 = tdx & 7;
        if (row < MS) {
            const float4* p = (const float4*)(s_feats + (size_t)row * CIN + l8 * 8);
            float4 a = p[0], c = p[1];
            float s = ((a.x + a.y) + (a.z + a.w)) + ((c.x + c.y) + (c.z + c.w));
            s += __shfl_xor(s, 1);
            s += __shfl_xor(s, 2);
            s += __shfl_xor(s, 4);
            if (l8 == 0) rs[row] = s;
        }
    }
}

// ---- main fused kernel ----
__global__ __launch_bounds__(512, 5)
void kpconv_mfma(const float* __restrict__ q_pts,
                 const float* __restrict__ s_pts,
                 const float* __restrict__ s_feats,
                 const int*   __restrict__ neigh,
                 const float* __restrict__ kpts,
                 const float* __restrict__ rowsum,
                 const short* __restrict__ whi,
                 const short* __restrict__ wlo,
                 float*       __restrict__ out)
{
    __shared__ __align__(16) short smem_s[2 * QB * SRH];   // 41984 B (hi + lo plane)
    __shared__ float norm_s[QB];
    __shared__ float kp_d[48];          // dedicated (kf region dies at round-0 dump)
    __shared__ int   cpk_d[QB * 32];    // [query-in-block][slot], survives all rounds

    const int tid  = threadIdx.x;
    const int lane = tid & 63;
    const int wv   = tid >> 6;       // 0..7
    const int blk  = blockIdx.x;
    const int k32  = lane & 31;
    const int quad = lane >> 4;
    const int half = lane >> 5;
    const int c15  = lane & 15;

    if (tid < KP * 3) kp_d[tid] = kpts[tid];
    __syncthreads();

    // ---------------- Prologue: gathers, norm, liveness mask, compaction ----------------
    float dxa[4], dya[4], dza[4];
    int   nva[4];
    {
        int nca[4], idxa[4];
        #pragma unroll
        for (int j = 0; j < 4; ++j) {
            const int n = blk * QB + wv * 4 + j;
            nca[j] = n < NQ ? n : NQ - 1;
        }
        #pragma unroll
        for (int j = 0; j < 4; ++j) idxa[j] = neigh[nca[j] * KNN + k32];
        #pragma unroll
        for (int j = 0; j < 4; ++j) {
            const float qx = q_pts[nca[j] * 3 + 0];
            const float qy = q_pts[nca[j] * 3 + 1];
            const float qz = q_pts[nca[j] * 3 + 2];
            bool valid = idxa[j] < MS;
            int  icv   = valid ? idxa[j] : MS - 1;
            float px = s_pts[icv * 3 + 0];
            float py = s_pts[icv * 3 + 1];
            float pz = s_pts[icv * 3 + 2];
            float rsv = rowsum[icv];
            dxa[j] = valid ? px - qx : 1e6f;
            dya[j] = valid ? py - qy : 1e6f;
            dza[j] = valid ? pz - qz : 1e6f;
            bool flag = valid && (rsv > 0.0f);
            unsigned long long b = __ballot(flag);      // halves duplicate each k
            int cnt = (int)(__popcll(b) >> 1);
            if (lane == 0) norm_s[wv * 4 + j] = 1.0f / (float)(cnt > 1 ? cnt : 1);

            // liveness sweep (values discarded; only the mask is kept)
            unsigned em = 0;
            #pragma unroll
            for (int p = 0; p < 8; ++p) {
                const int e = (p << 1) + half;
                if (e < KP) {
                    float ax = dxa[j] - kp_d[e * 3 + 0];
                    float ay = dya[j] - kp_d[e * 3 + 1];
                    float az = dza[j] - kp_d[e * 3 + 2];
                    float d2 = ax * ax + ay * ay + az * az + 1e-8f;
                    float hh = 1.0f - sqrtf(d2) * KP_EXT_INV;
                    em |= (hh > 0.0f ? 1u : 0u) << e;
                }
            }
            em |= (unsigned)__shfl_xor((int)em, 32);
            unsigned int kmask = (unsigned int)__ballot(em != 0);
            nva[j] = __popc(kmask);

            if (lane < KNN) {
                bool bit = (kmask >> k32) & 1u;
                unsigned lm = (1u << k32) - 1u;
                int pos = bit ? __popc(kmask & lm) : nva[j] + __popc((~kmask) & lm);
                cpk_d[(wv * 4 + j) * 32 + pos] = bit ? ((icv << 6) | k32) : 0;
            }
        }
    }
    __builtin_amdgcn_wave_barrier();

    // ---------------- Round-interleaved phase-1 + phase-2 ----------------
    const short8* wh = (const short8*)whi;
    const short8* wl = (const short8*)wlo;
    f32x4 acc0 = {0.f, 0.f, 0.f, 0.f};   // m-tile 0 (queries 0..15)
    f32x4 acc1 = {0.f, 0.f, 0.f, 0.f};   // m-tile 1 (queries 16..31)
    const int qA = c15;

    #pragma unroll
    for (int r = 0; r < RND; ++r) {
        const int pb = (5 * r) >> 1;     // 0, 2, 5
        float kfv5[4][RE];               // 20 AGPR-class accumulators

        #pragma unroll
        for (int j = 0; j < 4; ++j) {
            // recompute the 3 hreg pairs covering e in [5r, 5r+5)
            float hp[3];
            #pragma unroll
            for (int pi = 0; pi < 3; ++pi) {
                const int e = ((pb + pi) << 1) + half;
                float hh = 0.0f;
                if (e < KP) {
                    float ax = dxa[j] - kp_d[e * 3 + 0];
                    float ay = dya[j] - kp_d[e * 3 + 1];
                    float az = dza[j] - kp_d[e * 3 + 2];
                    float d2 = ax * ax + ay * ay + az * az + 1e-8f;
                    hh = 1.0f - sqrtf(d2) * KP_EXT_INV;
                    hh = hh > 0.0f ? hh : 0.0f;
                }
                hp[pi] = hh;
            }
            #pragma unroll
            for (int e5 = 0; e5 < RE; ++e5) kfv5[j][e5] = 0.0f;

            const int nv  = nva[j];
            const int nvr = (nv + 3) & ~3;
            const int* cq = cpk_d + (wv * 4 + j) * 32;

            int   pkc[4];
            float nfc[4];
            #pragma unroll
            for (int u = 0; u < 4; ++u) pkc[u] = __builtin_amdgcn_readfirstlane(cq[u]);
            #pragma unroll
            for (int u = 0; u < 4; ++u) nfc[u] = s_feats[(size_t)(pkc[u] >> 6) * CIN + lane];

            for (int base = 0; base < nvr; base += 4) {
                int   pkn[4];
                float nfn[4];
                #pragma unroll
                for (int u = 0; u < 4; ++u) {
                    int ii = base + 4 + u;
                    ii = ii < 31 ? ii : 31;          // in-bounds; pads hold 0 (safe)
                    pkn[u] = __builtin_amdgcn_readfirstlane(cq[ii]);
                }
                #pragma unroll
                for (int u = 0; u < 4; ++u) nfn[u] = s_feats[(size_t)(pkn[u] >> 6) * CIN + lane];

                #pragma unroll
                for (int u = 0; u < 4; ++u) {
                    const float f  = (base + u < nv) ? nfc[u] : 0.0f;
                    const int   kk = pkc[u] & 63;
                    #pragma unroll
                    for (int e5 = 0; e5 < RE; ++e5) {
                        const int e = 5 * r + e5;
                        float he = readlane_f(hp[(e >> 1) - pb], kk | ((e & 1) << 5));
                        kfv5[j][e5] += he * f;
                    }
                }
                #pragma unroll
                for (int u = 0; u < 4; ++u) { pkc[u] = pkn[u]; nfc[u] = nfn[u]; }
            }
        }

        __syncthreads();   // all waves done reading kf of round r-1 (GEMM below)
        // dump: row q, element i = e5*64 + lane; hi plane + lo plane
        #pragma unroll
        for (int j = 0; j < 4; ++j) {
            const int q = 4 * wv + j;
            #pragma unroll
            for (int e5 = 0; e5 < RE; ++e5) {
                float v  = kfv5[j][e5];
                short hi = f32_bf16(v);
                short lo = f32_bf16(v - bf16_f32(hi));
                smem_s[q * SRH + e5 * 64 + lane]          = hi;
                smem_s[LO_OFF + q * SRH + e5 * 64 + lane] = lo;
            }
        }
        __syncthreads();

        #pragma unroll 2
        for (int kb = 0; kb < KBR; ++kb) {
            const int ai = kb * 32 + quad * 8;
            short8 ah0 = *(const short8*)(smem_s + qA * SRH + ai);
            short8 al0 = *(const short8*)(smem_s + LO_OFF + qA * SRH + ai);
            short8 ah1 = *(const short8*)(smem_s + (16 + qA) * SRH + ai);
            short8 al1 = *(const short8*)(smem_s + LO_OFF + (16 + qA) * SRH + ai);

            const int kbg = r * KBR + kb;
            short8 bh = wh[(wv * KBT + kbg) * 64 + lane];
            short8 bl = wl[(wv * KBT + kbg) * 64 + lane];

            acc0 = __builtin_amdgcn_mfma_f32_16x16x32_bf16(ah0, bh, acc0, 0, 0, 0);
            acc1 = __builtin_amdgcn_mfma_f32_16x16x32_bf16(ah1, bh, acc1, 0, 0, 0);
            acc0 = __builtin_amdgcn_mfma_f32_16x16x32_bf16(ah0, bl, acc0, 0, 0, 0);
            acc1 = __builtin_amdgcn_mfma_f32_16x16x32_bf16(ah1, bl, acc1, 0, 0, 0);
            acc0 = __builtin_amdgcn_mfma_f32_16x16x32_bf16(al0, bh, acc0, 0, 0, 0);
            acc1 = __builtin_amdgcn_mfma_f32_16x16x32_bf16(al1, bh, acc1, 0, 0, 0);
        }
    }

    // epilogue: D row m = quad*4+rr (query within tile), col = lane&15
    const int oc = c15;
    #pragma unroll
    for (int rr = 0; rr < 4; ++rr) {
        int qm0 = quad * 4 + rr;
        int qm1 = 16 + qm0;
        int n0 = blk * QB + qm0;
        int n1 = blk * QB + qm1;
        if (n0 < NQ) out[(size_t)n0 * COUT + wv * 16 + oc] = acc0[rr] * norm_s[qm0];
        if (n1 < NQ) out[(size_t)n1 * COUT + wv * 16 + oc] = acc1[rr] * norm_s[qm1];
    }
}

// ---- fallback (no workspace; R2-verified structure) ----
__global__ __launch_bounds__(256, 6)
void kpconv_fallback(const float* __restrict__ q_pts,
                     const float* __restrict__ s_pts,
                     const float* __restrict__ s_feats,
                     const int*   __restrict__ neigh,
                     const float* __restrict__ W,
                     const float* __restrict__ kpts,
                     float*       __restrict__ out)
{
    constexpr int QBF = 16, CHUNK_I = 320, NPAIR = 160;
    __shared__ __align__(16) float smem[NPAIR * 32];
    __shared__ float norm_s[QBF];
    float (*h_lds)[KNN][20] = (float (*)[KNN][20])smem;
    float (*dxyz)[KNN][3]   = (float (*)[KNN][3])(smem + 2560);
    int*   idxl             = (int*)(smem + 2944);
    float* kp_s             = smem + 3072;

    const int tid = threadIdx.x, lane = tid & 63, wv = tid >> 6, blk = blockIdx.x;
    const int k32 = lane & 31, half = lane >> 5;
    if (tid < KP * 3) kp_s[tid] = kpts[tid];
    __syncthreads();
    float kfv[4][KP];

    #pragma unroll
    for (int j = 0; j < 4; ++j) {
        const int q = wv * 4 + j, n = blk * QBF + q;
        const float qx = q_pts[n*3], qy = q_pts[n*3+1], qz = q_pts[n*3+2];
        if (lane < KNN) {
            int idx = neigh[n * KNN + k32];
            idxl[wv * KNN + k32] = idx;
            bool valid = idx < MS;
            int ic = valid ? idx : MS - 1;
            dxyz[wv][k32][0] = valid ? s_pts[ic*3]   - qx : 1e6f;
            dxyz[wv][k32][1] = valid ? s_pts[ic*3+1] - qy : 1e6f;
            dxyz[wv][k32][2] = valid ? s_pts[ic*3+2] - qz : 1e6f;
        }
        __builtin_amdgcn_wave_barrier();
        const float dx = dxyz[wv][k32][0], dy = dxyz[wv][k32][1], dz = dxyz[wv][k32][2];
        float om = 0.0f;
        #pragma unroll
        for (int p = 0; p < 8; ++p) {
            const int e = (p << 1) + half;
            if (e < KP) {
                float ax = dx - kp_s[e*3], ay = dy - kp_s[e*3+1], az = dz - kp_s[e*3+2];
                float hh = 1.0f - sqrtf(ax*ax + ay*ay + az*az + 1e-8f) * KP_EXT_INV;
                hh = hh > 0.0f ? hh : 0.0f;
                h_lds[wv][k32][e] = hh;
                om = fmaxf(om, hh);
            }
        }
        om = fmaxf(om, __shfl_xor(om, 32));
        unsigned int kmask = (unsigned int)__ballot(om > 0.0f);
        __builtin_amdgcn_wave_barrier();
        {
            int idx = idxl[wv * KNN + k32];
            bool valid = idx < MS;
            int ic = valid ? idx : MS - 1;
            const float4* rp = (const float4*)(s_feats + (size_t)ic * CIN + half * 32);
            float4 s4 = rp[0];
            #pragma unroll
            for (int t = 1; t < 8; ++t) { float4 a = rp[t]; s4.x+=a.x; s4.y+=a.y; s4.z+=a.z; s4.w+=a.w; }
            float s = (s4.x + s4.y) + (s4.z + s4.w);
            s += __shfl_xor(s, 32);
            unsigned long long b = __ballot(valid && (s > 0.0f));
            int cnt = (int)(__popcll(b) >> 1);
            if (lane == 0) norm_s[q] = 1.0f / (float)(cnt > 1 ? cnt : 1);
        }
        #pragma unroll
        for (int e = 0; e < KP; ++e) kfv[j][e] = 0.0f;
        unsigned int mk = kmask;
        while (mk) {
            int k = __builtin_ctz(mk); mk &= mk - 1;
            int idx2 = idxl[wv * KNN + k];
            int ic2 = idx2 < MS ? idx2 : MS - 1;
            float nf = s_feats[(size_t)ic2 * CIN + lane];
            const float4* hr = (const float4*)(&h_lds[wv][k][0]);
            float4 h0 = hr[0], h1 = hr[1], h2 = hr[2], h3 = hr[3];
            kfv[j][0]+=h0.x*nf; kfv[j][1]+=h0.y*nf; kfv[j][2]+=h0.z*nf; kfv[j][3]+=h0.w*nf;
            kfv[j][4]+=h1.x*nf; kfv[j][5]+=h1.y*nf; kfv[j][6]+=h1.z*nf; kfv[j][7]+=h1.w*nf;
            kfv[j][8]+=h2.x*nf; kfv[j][9]+=h2.y*nf; kfv[j][10]+=h2.z*nf; kfv[j][11]+=h2.w*nf;
            kfv[j][12]+=h3.x*nf; kfv[j][13]+=h3.y*nf; kfv[j][14]+=h3.z*nf;
        }
    }

    const int o4 = tid & 31, qi = tid >> 5, q0 = qi * 2, q1 = q0 + 1;
    float4 tot0 = make_float4(0,0,0,0), tot1 = make_float4(0,0,0,0);
    #pragma unroll
    for (int r = 0; r < 3; ++r) {
        __syncthreads();
        #pragma unroll
        for (int j = 0; j < 4; ++j) {
            const int q = wv * 4 + j;
            #pragma unroll
            for (int e5 = 0; e5 < 5; ++e5) {
                int i = e5 * CIN + lane, pr = i >> 1, m = pr & 14;
                smem[pr * 32 + ((q ^ m) << 1) + (i & 1)] = kfv[j][r * 5 + e5];
            }
        }
        __syncthreads();
        const float* wb = W + (size_t)(r * CHUNK_I) * COUT + (o4 << 2);
        float4 acc0 = make_float4(0,0,0,0), acc1 = make_float4(0,0,0,0);
        #pragma unroll 4
        for (int p = 0; p < NPAIR; ++p) {
            float4 kk = *(const float4*)(smem + p * 32 + ((q0 ^ (p & 14)) << 1));
            float4 w0 = *(const float4*)(wb + (size_t)(2*p) * COUT);
            float4 w1 = *(const float4*)(wb + (size_t)(2*p+1) * COUT);
            acc0.x+=w0.x*kk.x; acc0.y+=w0.y*kk.x; acc0.z+=w0.z*kk.x; acc0.w+=w0.w*kk.x;
            acc1.x+=w0.x*kk.z; acc1.y+=w0.y*kk.z; acc1.z+=w0.z*kk.z; acc1.w+=w0.w*kk.z;
            acc0.x+=w1.x*kk.y; acc0.y+=w1.y*kk.y; acc0.z+=w1.z*kk.y; acc0.w+=w1.w*kk.y;
            acc1.x+=w1.x*kk.w; acc1.y+=w1.y*kk.w; acc1.z+=w1.z*kk.w; acc1.w+=w1.w*kk.w;
        }
        tot0.x+=acc0.x; tot0.y+=acc0.y; tot0.z+=acc0.z; tot0.w+=acc0.w;
        tot1.x+=acc1.x; tot1.y+=acc1.y; tot1.z+=acc1.z; tot1.w+=acc1.w;
    }
    const float nm0 = norm_s[q0], nm1 = norm_s[q1];
    const size_t base = (size_t)(blk * QBF) * COUT + (o4 << 2);
    *(float4*)(out + base + (size_t)q0 * COUT) =
        make_float4(tot0.x*nm0, tot0.y*nm0, tot0.z*nm0, tot0.w*nm0);
    *(float4*)(out + base + (size_t)q1 * COUT) =
        make_float4(tot1.x*nm1, tot1.y*nm1, tot1.z*nm1, tot1.w*nm1);
}

extern "C" void kernel_launch(void* const* d_in, const int* in_sizes, int n_in,
                              void* d_out, int out_size, void* d_ws, size_t ws_size,
                              hipStream_t stream) {
    const float* q_pts   = (const float*)d_in[0];
    const float* s_pts   = (const float*)d_in[1];
    const float* s_feats = (const float*)d_in[2];
    const int*   neigh   = (const int*)d_in[3];
    const float* W       = (const float*)d_in[4];
    const float* kpts    = (const float*)d_in[5];
    float* outp = (float*)d_out;

    dim3 mgrid((NQ + QB - 1) / QB);   // 1563
    dim3 mblock(512);

    if (ws_size >= WSB_END) {
        float* rs  = (float*)d_ws;
        short* whi = (short*)((char*)d_ws + WSB_HI);
        short* wlo = (short*)((char*)d_ws + WSB_LO);
        int rs_blocks = (MS * 8 + 255) / 256;
        hipLaunchKernelGGL(prep_basic, dim3(60 + rs_blocks), dim3(256), 0, stream,
                           s_feats, W, rs, whi, wlo);
        hipLaunchKernelGGL(kpconv_mfma, mgrid, mblock, 0, stream,
                           q_pts, s_pts, s_feats, neigh, kpts, rs, whi, wlo, outp);
    } else {
        hipLaunchKernelGGL(kpconv_fallback, dim3(NQ / 16), dim3(256), 0, stream,
                           q_pts, s_pts, s_feats, neigh, W, kpts, outp);
    }
}